// Round 11
// baseline (261.188 us; speedup 1.0000x reference)
//
#include <hip/hip_runtime.h>
#include <math.h>

#define NOBS  192
#define MTEST 64
#define NF    256
#define KP    32
#define DD    8
#define NB    32                   /* Cholesky block */
#define NBLK  6
#define SB    69                   /* Bm row stride: 64 Kox + ys + ones + 3 pad */
#define PSTR  36                   /* Pn/Mi row stride (16B aligned) */
#define NTHR  768
#define NWAVE 12

/* padded packed-lower-triangle offset: rows padded to multiple of 4 floats so
   every row is 16B-aligned. PROF(191)+192 = 18816. */
__device__ __host__ __forceinline__ int PROF(int i) {
  int a = i >> 2, m = i & 3;
  return ((a + 1) * ((a << 1) + m)) << 2;
}

/* ws layout (float offsets) */
#define WS_C   0                      /* 65536 */
#define WS_S   (WS_C + NF*NF)         /* 13248 */
#define WS_LP  (WS_S + NOBS*SB)       /* 18816 packed Koo image */
#define WS_BB  (WS_LP + 18816)        /* 13248 Bm image; end 110848 floats */

// K1 (k0 fused): 8x8 function tile per block (256 thr). Computes z'=x/rho*sqrt(log2e),
// mh=-0.5||z'||^2 on the fly. i-side staged in LDS; thread owns one (j,q) point.
// C[i,j] = sum_{p,q} A[i,p]A[j,q] exp2(zp.zq + mh_p + mh_q)
__global__ __launch_bounds__(256) void k1_C(
    const float* __restrict__ Xo, const float* __restrict__ Ao,
    const float* __restrict__ Xt, const float* __restrict__ At,
    const float* __restrict__ rho_base, float* __restrict__ C) {
  // decode linear upper-triangle block index -> (ti, tj), ti<=tj (528 blocks)
  int tt = blockIdx.x;
  int ti = 0, len = 32, rm = tt;
  while (rm >= len) { rm -= len; ++ti; --len; }
  int tj = ti + rm;

  __shared__ float Zi[8 * KP * DD];   // 8KB
  __shared__ float Ai[8 * KP];
  __shared__ float MHi[8 * KP];
  int th = threadIdx.x;
  const float s = 1.2011224087864498f;  // sqrt(log2(e))
  float4 rr0 = *(const float4*)(rho_base);
  float4 rr1 = *(const float4*)(rho_base + 4);
  float i0 = s / rr0.x, i1 = s / rr0.y, i2 = s / rr0.z, i3 = s / rr0.w;
  float i4 = s / rr1.x, i5 = s / rr1.y, i6 = s / rr1.z, i7 = s / rr1.w;

  // i-side point (staged to LDS): global point index gpi = ti*256 + th
  {
    int gpi = ti * 256 + th;
    const float* xp = (gpi < NOBS * KP) ? (Xo + gpi * DD) : (Xt + (gpi - NOBS * KP) * DD);
    float4 x0 = *(const float4*)(xp);
    float4 x1 = *(const float4*)(xp + 4);
    float z0 = x0.x * i0, z1 = x0.y * i1, z2 = x0.z * i2, z3 = x0.w * i3;
    float z4 = x1.x * i4, z5 = x1.y * i5, z6 = x1.z * i6, z7 = x1.w * i7;
    float n = z0 * z0 + z1 * z1 + z2 * z2 + z3 * z3 +
              z4 * z4 + z5 * z5 + z6 * z6 + z7 * z7;
    *(float4*)&Zi[th * DD] = make_float4(z0, z1, z2, z3);
    *(float4*)&Zi[th * DD + 4] = make_float4(z4, z5, z6, z7);
    MHi[th] = -0.5f * n;
    Ai[th] = (gpi < NOBS * KP) ? Ao[gpi] : At[gpi - NOBS * KP];
  }
  // j-side point (kept in registers): gpj = tj*256 + th
  float4 zq0, zq1;
  float aq, mq;
  {
    int gpj = tj * 256 + th;
    const float* xp = (gpj < NOBS * KP) ? (Xo + gpj * DD) : (Xt + (gpj - NOBS * KP) * DD);
    float4 x0 = *(const float4*)(xp);
    float4 x1 = *(const float4*)(xp + 4);
    zq0 = make_float4(x0.x * i0, x0.y * i1, x0.z * i2, x0.w * i3);
    zq1 = make_float4(x1.x * i4, x1.y * i5, x1.z * i6, x1.w * i7);
    float n = zq0.x * zq0.x + zq0.y * zq0.y + zq0.z * zq0.z + zq0.w * zq0.w +
              zq1.x * zq1.x + zq1.y * zq1.y + zq1.z * zq1.z + zq1.w * zq1.w;
    mq = -0.5f * n;
    aq = (gpj < NOBS * KP) ? Ao[gpj] : At[gpj - NOBS * KP];
  }
  __syncthreads();

  int q = th & 31;
  float acc[8];
#pragma unroll
  for (int ii = 0; ii < 8; ++ii) acc[ii] = 0.f;
#pragma unroll
  for (int ii = 0; ii < 8; ++ii) {
    float a_ = acc[ii];
#pragma unroll 8
    for (int p = 0; p < KP; ++p) {
      const float4* Zp = (const float4*)(Zi + (ii * KP + p) * DD);
      float4 zp0 = Zp[0], zp1 = Zp[1];
      float d = zp0.x * zq0.x;
      d = fmaf(zp0.y, zq0.y, d);
      d = fmaf(zp0.z, zq0.z, d);
      d = fmaf(zp0.w, zq0.w, d);
      d = fmaf(zp1.x, zq1.x, d);
      d = fmaf(zp1.y, zq1.y, d);
      d = fmaf(zp1.z, zq1.z, d);
      d = fmaf(zp1.w, zq1.w, d);
      float arg = d + MHi[ii * KP + p] + mq;
      float ex;
      asm("v_exp_f32 %0, %1" : "=v"(ex) : "v"(arg));  // 2^arg
      a_ = fmaf(Ai[ii * KP + p], ex, a_);
    }
    acc[ii] = a_;
  }
#pragma unroll
  for (int ii = 0; ii < 8; ++ii) {
    float v = acc[ii] * aq;
#pragma unroll
    for (int off = 16; off > 0; off >>= 1) v += __shfl_xor(v, off, 64);
    if (q == 0) {
      int fi = ti * 8 + ii, fj = tj * 8 + (th >> 5);
      C[fi * NF + fj] = v;
      C[fj * NF + fi] = v;
    }
  }
}

// K2: parallel build of the LDS images for k3: Lbuf = packed-padded lower
// triangle of Koo (nugget included, pads zeroed); Bbuf = [Kox | ys-b | 1 | 0].
__global__ __launch_bounds__(256) void k2_build(
    const float* __restrict__ Cm, const float* __restrict__ ys,
    const float* __restrict__ pb, const float* __restrict__ prho,
    const float* __restrict__ pg, const float* __restrict__ pnu,
    float* __restrict__ Lbuf, float* __restrict__ Bbuf) {
  int i = blockIdx.x;   // 0..191
  int t = threadIdx.x;
  float nu = pnu[0];
  float c2 = -0.72134752044448f / prho[0];  // -0.5*log2(e)/rho
  float gn = nu * pg[0];
  float qi = Cm[i * NF + i];
  int rowlen = (i & ~3) + 4;
  int base = PROF(i);
  for (int l = t; l < rowlen; l += 256) {
    float v = 0.f;
    if (l <= i) {
      float D2 = qi + Cm[l * NF + l] - 2.f * Cm[i * NF + l];
      D2 = D2 > 0.f ? D2 : 0.f;
      v = nu * exp2f(c2 * D2) + (l == i ? gn : 0.f);
    }
    Lbuf[base + l] = v;
  }
  if (t < SB) {
    float v;
    if (t < 64) {
      float D2 = qi + Cm[(NOBS + t) * NF + NOBS + t] - 2.f * Cm[i * NF + NOBS + t];
      D2 = D2 > 0.f ? D2 : 0.f;
      v = nu * exp2f(c2 * D2);
    } else if (t == 64) v = ys[i] - pb[0];
    else if (t == 65) v = 1.0f;
    else v = 0.f;
    Bbuf[i * SB + t] = v;
  }
}

// Phase A: wave-0 lanes 0..31 factor the 32x32 diag block at kbA in registers,
// then invert; inv(L11) rows land in MiB (stride PSTR).
__device__ __forceinline__ void phaseA(float* Lp, float* MiB, int kbA, int lane) {
  float row[32];
  int base = PROF(kbA + lane) + kbA;
#pragma unroll
  for (int c = 0; c < 32; c += 4) {
    float4 v = *(const float4*)&Lp[base + c];
    row[c] = v.x; row[c + 1] = v.y; row[c + 2] = v.z; row[c + 3] = v.w;
  }
#pragma unroll
  for (int j = 0; j < 32; ++j) {
    float dj = __shfl(row[j], j, 64);
    float rs = 1.0f / sqrtf(dj);
    float cl = row[j] * rs;
    row[j] = cl;
#pragma unroll
    for (int c = j + 1; c < 32; ++c)
      row[c] = fmaf(-cl, __shfl(cl, c, 64), row[c]);
  }
#pragma unroll
  for (int c = 0; c < 32; c += 4) {
    *(float4*)&MiB[lane * PSTR + c] =
        make_float4(row[c], row[c + 1], row[c + 2], row[c + 3]);
  }
  // triangular inverse: lane holds column `lane` of M = inv(L11)
  float x[32];
#pragma unroll
  for (int i2 = 0; i2 < 32; ++i2) {
    float vi = MiB[i2 * PSTR + lane];  // lane k holds L[i2][k]
    float acc = (i2 == lane) ? 1.0f : 0.0f;
#pragma unroll
    for (int k = 0; k < 32; ++k) {
      if (k < i2) acc = fmaf(-__shfl(vi, k, 64), x[k], acc);
    }
    x[i2] = acc / __shfl(vi, i2, 64);
  }
#pragma unroll
  for (int i2 = 0; i2 < 32; ++i2) MiB[i2 * PSTR + lane] = x[i2];
}

// K3: blocked Cholesky + fused 66-RHS forward solve, 12 waves, lookahead
// (Phase A(b+1) on wave 0 concurrent with block b's trailing updates).
// Raw LLVM attrs pin occupancy to exactly 3 waves/EU (VGPR budget 168) —
// __launch_bounds__ is deliberately absent (its implied occupancy attrs
// overrode amdgpu_waves_per_eu in R8/R10: VGPR stuck at 84 + 260KB spill).
__global__
__attribute__((amdgpu_flat_work_group_size(768, 768), amdgpu_waves_per_eu(3, 3)))
void k3_factor_solve(
    const float* __restrict__ Lsrc, const float* __restrict__ Bsrc,
    float* __restrict__ Sout) {
  __shared__ float Lp[18816];          // 75264 B
  __shared__ float Bm[NOBS * SB];      // 52992 B
  __shared__ float Pn[160 * PSTR];     // 23040 B
  __shared__ float Mi[2][32 * PSTR];   // 9216 B  (total 160512 B)

  int tid = threadIdx.x;
  int lane = tid & 63;
  int w = tid >> 6;

  // ---- load prebuilt images ----
  for (int e = tid; e < 18816 / 4; e += NTHR)
    ((float4*)Lp)[e] = ((const float4*)Lsrc)[e];
  for (int e = tid; e < (NOBS * SB) / 4; e += NTHR)
    ((float4*)Bm)[e] = ((const float4*)Bsrc)[e];
  __syncthreads();

  if (w == 0 && lane < 32) phaseA(Lp, Mi[0], 0, lane);
  __syncthreads();

  for (int b = 0; b < NBLK; ++b) {
    int kb = b * NB;
    int rem = NOBS - kb - NB;
    const float* Mc = Mi[b & 1];

    // ---- R1: panel L21 = A21*M^T -> Pn ; Y = M*B_b -> registers ----
    float yv[5];
    if (rem > 0) {
      int c = tid & 31;
      int rg = tid >> 5;  // 0..23
      float Mreg[32];
#pragma unroll
      for (int qq = 0; qq < 32; qq += 4) {
        float4 v = *(const float4*)&Mc[c * PSTR + qq];
        Mreg[qq] = v.x; Mreg[qq + 1] = v.y; Mreg[qq + 2] = v.z; Mreg[qq + 3] = v.w;
      }
#pragma unroll 7
      for (int rr = 0; rr < 7; ++rr) {
        int r = rg + rr * 24;
        if (r < rem) {
          int abase = PROF(kb + NB + r) + kb;
          float a0 = 0.f, a1 = 0.f, a2 = 0.f, a3 = 0.f;
#pragma unroll
          for (int qq = 0; qq < 32; qq += 4) {
            float4 av = *(const float4*)&Lp[abase + qq];
            a0 = fmaf(av.x, Mreg[qq], a0);
            a1 = fmaf(av.y, Mreg[qq + 1], a1);
            a2 = fmaf(av.z, Mreg[qq + 2], a2);
            a3 = fmaf(av.w, Mreg[qq + 3], a3);
          }
          Pn[r * PSTR + c] = (a0 + a1) + (a2 + a3);
        }
      }
    }
    if (tid < 512) {
      int r2 = tid >> 4, cg = tid & 15;
      float Mrow[32];
#pragma unroll
      for (int qq = 0; qq < 32; qq += 4) {
        float4 v = *(const float4*)&Mc[r2 * PSTR + qq];
        Mrow[qq] = v.x; Mrow[qq + 1] = v.y; Mrow[qq + 2] = v.z; Mrow[qq + 3] = v.w;
      }
#pragma unroll 5
      for (int jj = 0; jj < 5; ++jj) {
        int col = cg + 16 * jj;
        float a0 = 0.f, a1 = 0.f, a2 = 0.f, a3 = 0.f;
        if (col < SB) {
#pragma unroll
          for (int k = 0; k < 32; k += 4) {
            a0 = fmaf(Mrow[k],     Bm[(kb + k) * SB + col], a0);
            a1 = fmaf(Mrow[k + 1], Bm[(kb + k + 1) * SB + col], a1);
            a2 = fmaf(Mrow[k + 2], Bm[(kb + k + 2) * SB + col], a2);
            a3 = fmaf(Mrow[k + 3], Bm[(kb + k + 3) * SB + col], a3);
          }
        }
        yv[jj] = (a0 + a1) + (a2 + a3);
      }
    }
    __syncthreads();

    // ---- R2: write Y ; priority trailing update of the NEXT diag block ----
    if (tid < 512) {
      int r2 = tid >> 4, cg = tid & 15;
#pragma unroll 5
      for (int jj = 0; jj < 5; ++jj) {
        int col = cg + 16 * jj;
        if (col < SB) Bm[(kb + r2) * SB + col] = yv[jj];
      }
    }
    if (rem > 0) {
      for (int idx = tid; idx < 1024; idx += NTHR) {
        int r = idx >> 5, c = idx & 31;
        if (c <= r) {
          float a0 = 0.f, a1 = 0.f, a2 = 0.f, a3 = 0.f;
#pragma unroll
          for (int qq = 0; qq < 32; qq += 4) {
            float4 u = *(const float4*)&Pn[r * PSTR + qq];
            float4 vv = *(const float4*)&Pn[c * PSTR + qq];
            a0 = fmaf(u.x, vv.x, a0);
            a1 = fmaf(u.y, vv.y, a1);
            a2 = fmaf(u.z, vv.z, a2);
            a3 = fmaf(u.w, vv.w, a3);
          }
          Lp[PROF(kb + NB + r) + kb + NB + c] -= (a0 + a1) + (a2 + a3);
        }
      }
    }
    __syncthreads();

    // ---- R3: wave0 = Phase A(b+1) (lookahead) ; others = B-trail + C-rest ----
    if (rem > 0) {
      if (w == 0) {
        if (lane < 32) phaseA(Lp, Mi[(b + 1) & 1], kb + NB, lane);
      } else {
        int wp = w - 1;  // 0..10
        // B-trail cols 0..63: lane owns one column; Y rows cached in yc[]
        float yc[32];
#pragma unroll
        for (int k = 0; k < 32; ++k) yc[k] = Bm[(kb + k) * SB + lane];
        for (int rt = wp; rt < rem; rt += (NWAVE - 1)) {
          int gr = kb + NB + rt;
          float a0 = Bm[gr * SB + lane], a1 = 0.f;
#pragma unroll
          for (int k = 0; k < 32; k += 4) {
            float4 pv = *(const float4*)&Pn[rt * PSTR + k];  // broadcast
            a0 = fmaf(-pv.x, yc[k], a0);
            a1 = fmaf(-pv.y, yc[k + 1], a1);
            a0 = fmaf(-pv.z, yc[k + 2], a0);
            a1 = fmaf(-pv.w, yc[k + 3], a1);
          }
          Bm[gr * SB + lane] = a0 + a1;
        }
        // B-trail cols 64/65: thread-per-row scalar pass (no arrays)
        {
          int r65 = tid - 64;
          if (r65 < rem) {
            int gr = kb + NB + r65;
            float a64 = Bm[gr * SB + 64], a65 = Bm[gr * SB + 65];
#pragma unroll
            for (int qq = 0; qq < 32; qq += 4) {
              float4 pv = *(const float4*)&Pn[r65 * PSTR + qq];
              a64 = fmaf(-pv.x, Bm[(kb + qq) * SB + 64], a64);
              a65 = fmaf(-pv.x, Bm[(kb + qq) * SB + 65], a65);
              a64 = fmaf(-pv.y, Bm[(kb + qq + 1) * SB + 64], a64);
              a65 = fmaf(-pv.y, Bm[(kb + qq + 1) * SB + 65], a65);
              a64 = fmaf(-pv.z, Bm[(kb + qq + 2) * SB + 64], a64);
              a65 = fmaf(-pv.z, Bm[(kb + qq + 2) * SB + 65], a65);
              a64 = fmaf(-pv.w, Bm[(kb + qq + 3) * SB + 64], a64);
              a65 = fmaf(-pv.w, Bm[(kb + qq + 3) * SB + 65], a65);
            }
            Bm[gr * SB + 64] = a64;
            Bm[gr * SB + 65] = a65;
          }
        }
        // C-rest: trailing rows 32..rem-1 (priority rows 0..31 already done)
        for (int c0 = 0; c0 < rem; c0 += 64) {
          int cc = c0 + lane;
          int ccl = cc < 160 ? cc : 159;
          float Pc[32];
#pragma unroll
          for (int qq = 0; qq < 32; qq += 4) {
            float4 v = *(const float4*)&Pn[ccl * PSTR + qq];
            Pc[qq] = v.x; Pc[qq + 1] = v.y; Pc[qq + 2] = v.z; Pc[qq + 3] = v.w;
          }
          int rstart = c0 > 32 ? c0 : 32;
          for (int r = rstart + wp; r < rem; r += (NWAVE - 1)) {
            float a0 = 0.f, a1 = 0.f, a2 = 0.f, a3 = 0.f;
#pragma unroll
            for (int qq = 0; qq < 32; qq += 4) {
              float4 u = *(const float4*)&Pn[r * PSTR + qq];  // broadcast
              a0 = fmaf(u.x, Pc[qq], a0);
              a1 = fmaf(u.y, Pc[qq + 1], a1);
              a2 = fmaf(u.z, Pc[qq + 2], a2);
              a3 = fmaf(u.w, Pc[qq + 3], a3);
            }
            float tot = (a0 + a1) + (a2 + a3);
            if (cc <= r) {
              Lp[PROF(kb + NB + r) + kb + NB + cc] -= tot;
            }
          }
        }
      }
      __syncthreads();
    }
  }

  // ---- dump S = L^-1 [Kox | ys-b | 1 | pad] ----
  for (int e = tid; e < (NOBS * SB) / 4; e += NTHR)
    ((float4*)Sout)[e] = ((const float4*)Bm)[e];
}

// K4: epilogue across 64 blocks: mean, cov from S; Kxx recomputed from C.
__global__ __launch_bounds__(64) void k4_post(
    const float* __restrict__ S, const float* __restrict__ Cm,
    const float* __restrict__ pb, const float* __restrict__ prho,
    const float* __restrict__ pnu, float* __restrict__ out) {
  int a = blockIdx.x;
  int bb = threadIdx.x;
  float cv0 = 0.f, cv1 = 0.f, m0 = 0.f, m1 = 0.f;
  float ka0 = 0.f, ka1 = 0.f, kc0 = 0.f, kc1 = 0.f, d0 = 0.f, d1 = 0.f;
#pragma unroll 4
  for (int i = 0; i < NOBS; i += 2) {
    float sa0 = S[i * SB + a],        sb0 = S[i * SB + bb];
    float sy0 = S[i * SB + 64],       s10 = S[i * SB + 65];
    float sa1 = S[(i + 1) * SB + a],  sb1 = S[(i + 1) * SB + bb];
    float sy1 = S[(i + 1) * SB + 64], s11 = S[(i + 1) * SB + 65];
    cv0 = fmaf(sa0, sb0, cv0);  cv1 = fmaf(sa1, sb1, cv1);
    m0 = fmaf(sa0, sy0, m0);    m1 = fmaf(sa1, sy1, m1);
    ka0 = fmaf(sa0, s10, ka0);  ka1 = fmaf(sa1, s11, ka1);
    kc0 = fmaf(sb0, s10, kc0);  kc1 = fmaf(sb1, s11, kc1);
    d0 = fmaf(s10, s10, d0);    d1 = fmaf(s11, s11, d1);
  }
  float nu = pnu[0];
  float c2 = -0.72134752044448f / prho[0];
  float qa = Cm[(NOBS + a) * NF + NOBS + a];
  float qb = Cm[(NOBS + bb) * NF + NOBS + bb];
  float cab = Cm[(NOBS + a) * NF + NOBS + bb];
  float D2 = qa + qb - 2.f * cab;
  D2 = D2 > 0.f ? D2 : 0.f;
  float kxx = nu * exp2f(c2 * D2);
  float kbxa = 1.f - (ka0 + ka1);
  float kbxb = 1.f - (kc0 + kc1);
  float den = d0 + d1;
  out[MTEST + a * MTEST + bb] = kxx - (cv0 + cv1) + kbxa * kbxb / den;
  if (bb == 0) out[a] = pb[0] + (m0 + m1);
}

extern "C" void kernel_launch(void* const* d_in, const int* in_sizes, int n_in,
                              void* d_out, int out_size, void* d_ws, size_t ws_size,
                              hipStream_t stream) {
  const float* Xo = (const float*)d_in[0];
  const float* Ao = (const float*)d_in[1];
  const float* Xt = (const float*)d_in[2];
  const float* At = (const float*)d_in[3];
  const float* ys = (const float*)d_in[4];
  const float* rb = (const float*)d_in[5];
  const float* prho = (const float*)d_in[6];
  const float* pg = (const float*)d_in[7];
  const float* pnu = (const float*)d_in[8];
  const float* pb = (const float*)d_in[9];
  float* ws = (float*)d_ws;
  float* C = ws + WS_C;
  float* S = ws + WS_S;
  float* Lbuf = ws + WS_LP;
  float* Bbuf = ws + WS_BB;
  float* out = (float*)d_out;

  hipLaunchKernelGGL(k1_C, dim3(528), dim3(256), 0, stream,
                     Xo, Ao, Xt, At, rb, C);
  hipLaunchKernelGGL(k2_build, dim3(NOBS), dim3(256), 0, stream,
                     C, ys, pb, prho, pg, pnu, Lbuf, Bbuf);
  hipLaunchKernelGGL(k3_factor_solve, dim3(1), dim3(NTHR), 0, stream,
                     Lbuf, Bbuf, S);
  hipLaunchKernelGGL(k4_post, dim3(MTEST), dim3(MTEST), 0, stream, S, C, pb, prho, pnu, out);
}

// Round 12
// 226.549 us; speedup vs baseline: 1.1529x; 1.1529x over previous
//
#include <hip/hip_runtime.h>
#include <math.h>

#define NOBS  192
#define MTEST 64
#define NF    256
#define KP    32
#define DD    8
#define NB    32                   /* Cholesky block */
#define NBLK  6
#define SB    69                   /* Bm row stride: 64 Kox + ys + ones + 3 pad */
#define PSTR  36                   /* Pn/Mi row stride (16B aligned) */
#define NTHR  512
#define NWAVE 8

/* padded packed-lower-triangle offset: rows padded to multiple of 4 floats so
   every row is 16B-aligned. PROF(191)+192 = 18816. */
__device__ __host__ __forceinline__ int PROF(int i) {
  int a = i >> 2, m = i & 3;
  return ((a + 1) * ((a << 1) + m)) << 2;
}

/* ws layout (float offsets) */
#define WS_C   0                      /* 65536 */
#define WS_S   (WS_C + NF*NF)         /* 13248 */
#define WS_LP  (WS_S + NOBS*SB)       /* 18816 packed Koo image */
#define WS_BB  (WS_LP + 18816)        /* 13248 Bm image; end 110848 floats */

// K1 (k0 fused): 8x8 function tile per block (256 thr). Computes z'=x/rho*sqrt(log2e),
// mh=-0.5||z'||^2 on the fly. i-side staged in LDS; thread owns one (j,q) point.
// C[i,j] = sum_{p,q} A[i,p]A[j,q] exp2(zp.zq + mh_p + mh_q)
__global__ __launch_bounds__(256) void k1_C(
    const float* __restrict__ Xo, const float* __restrict__ Ao,
    const float* __restrict__ Xt, const float* __restrict__ At,
    const float* __restrict__ rho_base, float* __restrict__ C) {
  // decode linear upper-triangle block index -> (ti, tj), ti<=tj (528 blocks)
  int tt = blockIdx.x;
  int ti = 0, len = 32, rm = tt;
  while (rm >= len) { rm -= len; ++ti; --len; }
  int tj = ti + rm;

  __shared__ float Zi[8 * KP * DD];   // 8KB
  __shared__ float Ai[8 * KP];
  __shared__ float MHi[8 * KP];
  int th = threadIdx.x;
  const float s = 1.2011224087864498f;  // sqrt(log2(e))
  float4 rr0 = *(const float4*)(rho_base);
  float4 rr1 = *(const float4*)(rho_base + 4);
  float i0 = s / rr0.x, i1 = s / rr0.y, i2 = s / rr0.z, i3 = s / rr0.w;
  float i4 = s / rr1.x, i5 = s / rr1.y, i6 = s / rr1.z, i7 = s / rr1.w;

  // i-side point (staged to LDS): global point index gpi = ti*256 + th
  {
    int gpi = ti * 256 + th;
    const float* xp = (gpi < NOBS * KP) ? (Xo + gpi * DD) : (Xt + (gpi - NOBS * KP) * DD);
    float4 x0 = *(const float4*)(xp);
    float4 x1 = *(const float4*)(xp + 4);
    float z0 = x0.x * i0, z1 = x0.y * i1, z2 = x0.z * i2, z3 = x0.w * i3;
    float z4 = x1.x * i4, z5 = x1.y * i5, z6 = x1.z * i6, z7 = x1.w * i7;
    float n = z0 * z0 + z1 * z1 + z2 * z2 + z3 * z3 +
              z4 * z4 + z5 * z5 + z6 * z6 + z7 * z7;
    *(float4*)&Zi[th * DD] = make_float4(z0, z1, z2, z3);
    *(float4*)&Zi[th * DD + 4] = make_float4(z4, z5, z6, z7);
    MHi[th] = -0.5f * n;
    Ai[th] = (gpi < NOBS * KP) ? Ao[gpi] : At[gpi - NOBS * KP];
  }
  // j-side point (kept in registers): gpj = tj*256 + th
  float4 zq0, zq1;
  float aq, mq;
  {
    int gpj = tj * 256 + th;
    const float* xp = (gpj < NOBS * KP) ? (Xo + gpj * DD) : (Xt + (gpj - NOBS * KP) * DD);
    float4 x0 = *(const float4*)(xp);
    float4 x1 = *(const float4*)(xp + 4);
    zq0 = make_float4(x0.x * i0, x0.y * i1, x0.z * i2, x0.w * i3);
    zq1 = make_float4(x1.x * i4, x1.y * i5, x1.z * i6, x1.w * i7);
    float n = zq0.x * zq0.x + zq0.y * zq0.y + zq0.z * zq0.z + zq0.w * zq0.w +
              zq1.x * zq1.x + zq1.y * zq1.y + zq1.z * zq1.z + zq1.w * zq1.w;
    mq = -0.5f * n;
    aq = (gpj < NOBS * KP) ? Ao[gpj] : At[gpj - NOBS * KP];
  }
  __syncthreads();

  int q = th & 31;
  float acc[8];
#pragma unroll
  for (int ii = 0; ii < 8; ++ii) acc[ii] = 0.f;
#pragma unroll
  for (int ii = 0; ii < 8; ++ii) {
    float a_ = acc[ii];
#pragma unroll 8
    for (int p = 0; p < KP; ++p) {
      const float4* Zp = (const float4*)(Zi + (ii * KP + p) * DD);
      float4 zp0 = Zp[0], zp1 = Zp[1];
      float d = zp0.x * zq0.x;
      d = fmaf(zp0.y, zq0.y, d);
      d = fmaf(zp0.z, zq0.z, d);
      d = fmaf(zp0.w, zq0.w, d);
      d = fmaf(zp1.x, zq1.x, d);
      d = fmaf(zp1.y, zq1.y, d);
      d = fmaf(zp1.z, zq1.z, d);
      d = fmaf(zp1.w, zq1.w, d);
      float arg = d + MHi[ii * KP + p] + mq;
      float ex;
      asm("v_exp_f32 %0, %1" : "=v"(ex) : "v"(arg));  // 2^arg
      a_ = fmaf(Ai[ii * KP + p], ex, a_);
    }
    acc[ii] = a_;
  }
#pragma unroll
  for (int ii = 0; ii < 8; ++ii) {
    float v = acc[ii] * aq;
#pragma unroll
    for (int off = 16; off > 0; off >>= 1) v += __shfl_xor(v, off, 64);
    if (q == 0) {
      int fi = ti * 8 + ii, fj = tj * 8 + (th >> 5);
      C[fi * NF + fj] = v;
      C[fj * NF + fi] = v;
    }
  }
}

// K2: parallel build of the LDS images for k3: Lbuf = packed-padded lower
// triangle of Koo (nugget included, pads zeroed); Bbuf = [Kox | ys-b | 1 | 0].
__global__ __launch_bounds__(256) void k2_build(
    const float* __restrict__ Cm, const float* __restrict__ ys,
    const float* __restrict__ pb, const float* __restrict__ prho,
    const float* __restrict__ pg, const float* __restrict__ pnu,
    float* __restrict__ Lbuf, float* __restrict__ Bbuf) {
  int i = blockIdx.x;   // 0..191
  int t = threadIdx.x;
  float nu = pnu[0];
  float c2 = -0.72134752044448f / prho[0];  // -0.5*log2(e)/rho
  float gn = nu * pg[0];
  float qi = Cm[i * NF + i];
  int rowlen = (i & ~3) + 4;
  int base = PROF(i);
  for (int l = t; l < rowlen; l += 256) {
    float v = 0.f;
    if (l <= i) {
      float D2 = qi + Cm[l * NF + l] - 2.f * Cm[i * NF + l];
      D2 = D2 > 0.f ? D2 : 0.f;
      v = nu * exp2f(c2 * D2) + (l == i ? gn : 0.f);
    }
    Lbuf[base + l] = v;
  }
  if (t < SB) {
    float v;
    if (t < 64) {
      float D2 = qi + Cm[(NOBS + t) * NF + NOBS + t] - 2.f * Cm[i * NF + NOBS + t];
      D2 = D2 > 0.f ? D2 : 0.f;
      v = nu * exp2f(c2 * D2);
    } else if (t == 64) v = ys[i] - pb[0];
    else if (t == 65) v = 1.0f;
    else v = 0.f;
    Bbuf[i * SB + t] = v;
  }
}

// Phase A: wave-0 lanes 0..31 factor the 32x32 diag block at kbA in registers,
// then invert; inv(L11) rows land in MiB (stride PSTR).
__device__ __forceinline__ void phaseA(float* Lp, float* MiB, int kbA, int lane) {
  float row[32];
  int base = PROF(kbA + lane) + kbA;
#pragma unroll
  for (int c = 0; c < 32; c += 4) {
    float4 v = *(const float4*)&Lp[base + c];
    row[c] = v.x; row[c + 1] = v.y; row[c + 2] = v.z; row[c + 3] = v.w;
  }
#pragma unroll
  for (int j = 0; j < 32; ++j) {
    float dj = __shfl(row[j], j, 64);
    float rs = 1.0f / sqrtf(dj);
    float cl = row[j] * rs;
    row[j] = cl;
#pragma unroll
    for (int c = j + 1; c < 32; ++c)
      row[c] = fmaf(-cl, __shfl(cl, c, 64), row[c]);
  }
#pragma unroll
  for (int c = 0; c < 32; c += 4) {
    *(float4*)&MiB[lane * PSTR + c] =
        make_float4(row[c], row[c + 1], row[c + 2], row[c + 3]);
  }
  // triangular inverse: lane holds column `lane` of M = inv(L11)
  float x[32];
#pragma unroll
  for (int i2 = 0; i2 < 32; ++i2) {
    float vi = MiB[i2 * PSTR + lane];  // lane k holds L[i2][k]
    float acc = (i2 == lane) ? 1.0f : 0.0f;
#pragma unroll
    for (int k = 0; k < 32; ++k) {
      if (k < i2) acc = fmaf(-__shfl(vi, k, 64), x[k], acc);
    }
    x[i2] = acc / __shfl(vi, i2, 64);
  }
#pragma unroll
  for (int i2 = 0; i2 < 32; ++i2) MiB[i2 * PSTR + lane] = x[i2];
}

// K3: blocked Cholesky + fused 66-RHS forward solve, 8 waves (512 thr —
// the empirically spill-free config: R2/R5 showed VGPR=128, WRITE_SIZE=53KB),
// with lookahead: Phase A(b+1) on wave 0 concurrent with block b's trailing.
__global__ __launch_bounds__(NTHR) void k3_factor_solve(
    const float* __restrict__ Lsrc, const float* __restrict__ Bsrc,
    float* __restrict__ Sout) {
  __shared__ float Lp[18816];          // 75264 B
  __shared__ float Bm[NOBS * SB];      // 52992 B
  __shared__ float Pn[160 * PSTR];     // 23040 B
  __shared__ float Mi[2][32 * PSTR];   // 9216 B  (total 160512 B)

  int tid = threadIdx.x;
  int lane = tid & 63;
  int w = tid >> 6;

  // ---- load prebuilt images ----
  for (int e = tid; e < 18816 / 4; e += NTHR)
    ((float4*)Lp)[e] = ((const float4*)Lsrc)[e];
  for (int e = tid; e < (NOBS * SB) / 4; e += NTHR)
    ((float4*)Bm)[e] = ((const float4*)Bsrc)[e];
  __syncthreads();

  if (w == 0 && lane < 32) phaseA(Lp, Mi[0], 0, lane);
  __syncthreads();

  for (int b = 0; b < NBLK; ++b) {
    int kb = b * NB;
    int rem = NOBS - kb - NB;
    const float* Mc = Mi[b & 1];

    // ---- R1: panel L21 = A21*M^T -> Pn ; then Y = M*B_b -> registers ----
    float yv[5];
    if (rem > 0) {
      int c = tid & 31;
      int rg = tid >> 5;  // 0..15
      float Mreg[32];
#pragma unroll
      for (int qq = 0; qq < 32; qq += 4) {
        float4 v = *(const float4*)&Mc[c * PSTR + qq];
        Mreg[qq] = v.x; Mreg[qq + 1] = v.y; Mreg[qq + 2] = v.z; Mreg[qq + 3] = v.w;
      }
#pragma unroll 10
      for (int rr = 0; rr < 10; ++rr) {
        int r = rg + rr * 16;
        if (r < rem) {
          int abase = PROF(kb + NB + r) + kb;
          float a0 = 0.f, a1 = 0.f, a2 = 0.f, a3 = 0.f;
#pragma unroll
          for (int qq = 0; qq < 32; qq += 4) {
            float4 av = *(const float4*)&Lp[abase + qq];
            a0 = fmaf(av.x, Mreg[qq], a0);
            a1 = fmaf(av.y, Mreg[qq + 1], a1);
            a2 = fmaf(av.z, Mreg[qq + 2], a2);
            a3 = fmaf(av.w, Mreg[qq + 3], a3);
          }
          Pn[r * PSTR + c] = (a0 + a1) + (a2 + a3);
        }
      }
    }
    {
      int r2 = tid >> 4, cg = tid & 15;
      float Mrow[32];
#pragma unroll
      for (int qq = 0; qq < 32; qq += 4) {
        float4 v = *(const float4*)&Mc[r2 * PSTR + qq];
        Mrow[qq] = v.x; Mrow[qq + 1] = v.y; Mrow[qq + 2] = v.z; Mrow[qq + 3] = v.w;
      }
#pragma unroll 5
      for (int jj = 0; jj < 5; ++jj) {
        int col = cg + 16 * jj;
        float a0 = 0.f, a1 = 0.f, a2 = 0.f, a3 = 0.f;
        if (col < SB) {
#pragma unroll
          for (int k = 0; k < 32; k += 4) {
            a0 = fmaf(Mrow[k],     Bm[(kb + k) * SB + col], a0);
            a1 = fmaf(Mrow[k + 1], Bm[(kb + k + 1) * SB + col], a1);
            a2 = fmaf(Mrow[k + 2], Bm[(kb + k + 2) * SB + col], a2);
            a3 = fmaf(Mrow[k + 3], Bm[(kb + k + 3) * SB + col], a3);
          }
        }
        yv[jj] = (a0 + a1) + (a2 + a3);
      }
    }
    __syncthreads();

    // ---- R2: write Y ; priority trailing update of the NEXT diag block ----
    {
      int r2 = tid >> 4, cg = tid & 15;
#pragma unroll 5
      for (int jj = 0; jj < 5; ++jj) {
        int col = cg + 16 * jj;
        if (col < SB) Bm[(kb + r2) * SB + col] = yv[jj];
      }
    }
    if (rem > 0) {
      for (int idx = tid; idx < 1024; idx += NTHR) {
        int r = idx >> 5, c = idx & 31;
        if (c <= r) {
          float a0 = 0.f, a1 = 0.f, a2 = 0.f, a3 = 0.f;
#pragma unroll
          for (int qq = 0; qq < 32; qq += 4) {
            float4 u = *(const float4*)&Pn[r * PSTR + qq];
            float4 vv = *(const float4*)&Pn[c * PSTR + qq];
            a0 = fmaf(u.x, vv.x, a0);
            a1 = fmaf(u.y, vv.y, a1);
            a2 = fmaf(u.z, vv.z, a2);
            a3 = fmaf(u.w, vv.w, a3);
          }
          Lp[PROF(kb + NB + r) + kb + NB + c] -= (a0 + a1) + (a2 + a3);
        }
      }
    }
    __syncthreads();

    // ---- R3: wave0 = Phase A(b+1) (lookahead) ; others = B-trail + C-rest ----
    if (rem > 0) {
      if (w == 0) {
        if (lane < 32) phaseA(Lp, Mi[(b + 1) & 1], kb + NB, lane);
      } else {
        int wp = w - 1;  // 0..6
        // B-trail cols 0..63: lane owns one column; Y rows cached in yc[]
        float yc[32];
#pragma unroll
        for (int k = 0; k < 32; ++k) yc[k] = Bm[(kb + k) * SB + lane];
        for (int rt = wp; rt < rem; rt += (NWAVE - 1)) {
          int gr = kb + NB + rt;
          float a0 = Bm[gr * SB + lane], a1 = 0.f;
#pragma unroll
          for (int k = 0; k < 32; k += 4) {
            float4 pv = *(const float4*)&Pn[rt * PSTR + k];  // broadcast
            a0 = fmaf(-pv.x, yc[k], a0);
            a1 = fmaf(-pv.y, yc[k + 1], a1);
            a0 = fmaf(-pv.z, yc[k + 2], a0);
            a1 = fmaf(-pv.w, yc[k + 3], a1);
          }
          Bm[gr * SB + lane] = a0 + a1;
        }
        // B-trail cols 64/65: thread-per-row scalar pass (threads 64..223,
        // i.e. waves 1..3 — never wave 0)
        {
          int r65 = tid - 64;
          if (r65 >= 0 && r65 < rem) {
            int gr = kb + NB + r65;
            float a64 = Bm[gr * SB + 64], a65 = Bm[gr * SB + 65];
#pragma unroll
            for (int qq = 0; qq < 32; qq += 4) {
              float4 pv = *(const float4*)&Pn[r65 * PSTR + qq];
              a64 = fmaf(-pv.x, Bm[(kb + qq) * SB + 64], a64);
              a65 = fmaf(-pv.x, Bm[(kb + qq) * SB + 65], a65);
              a64 = fmaf(-pv.y, Bm[(kb + qq + 1) * SB + 64], a64);
              a65 = fmaf(-pv.y, Bm[(kb + qq + 1) * SB + 65], a65);
              a64 = fmaf(-pv.z, Bm[(kb + qq + 2) * SB + 64], a64);
              a65 = fmaf(-pv.z, Bm[(kb + qq + 2) * SB + 65], a65);
              a64 = fmaf(-pv.w, Bm[(kb + qq + 3) * SB + 64], a64);
              a65 = fmaf(-pv.w, Bm[(kb + qq + 3) * SB + 65], a65);
            }
            Bm[gr * SB + 64] = a64;
            Bm[gr * SB + 65] = a65;
          }
        }
        // C-rest: trailing rows 32..rem-1 (priority rows 0..31 already done)
        for (int c0 = 0; c0 < rem; c0 += 64) {
          int cc = c0 + lane;
          int ccl = cc < 160 ? cc : 159;
          float Pc[32];
#pragma unroll
          for (int qq = 0; qq < 32; qq += 4) {
            float4 v = *(const float4*)&Pn[ccl * PSTR + qq];
            Pc[qq] = v.x; Pc[qq + 1] = v.y; Pc[qq + 2] = v.z; Pc[qq + 3] = v.w;
          }
          int rstart = c0 > 32 ? c0 : 32;
          for (int r = rstart + wp; r < rem; r += (NWAVE - 1)) {
            float a0 = 0.f, a1 = 0.f, a2 = 0.f, a3 = 0.f;
#pragma unroll
            for (int qq = 0; qq < 32; qq += 4) {
              float4 u = *(const float4*)&Pn[r * PSTR + qq];  // broadcast
              a0 = fmaf(u.x, Pc[qq], a0);
              a1 = fmaf(u.y, Pc[qq + 1], a1);
              a2 = fmaf(u.z, Pc[qq + 2], a2);
              a3 = fmaf(u.w, Pc[qq + 3], a3);
            }
            float tot = (a0 + a1) + (a2 + a3);
            if (cc <= r) {
              Lp[PROF(kb + NB + r) + kb + NB + cc] -= tot;
            }
          }
        }
      }
      __syncthreads();
    }
  }

  // ---- dump S = L^-1 [Kox | ys-b | 1 | pad] ----
  for (int e = tid; e < (NOBS * SB) / 4; e += NTHR)
    ((float4*)Sout)[e] = ((const float4*)Bm)[e];
}

// K4: epilogue across 64 blocks: mean, cov from S; Kxx recomputed from C.
__global__ __launch_bounds__(64) void k4_post(
    const float* __restrict__ S, const float* __restrict__ Cm,
    const float* __restrict__ pb, const float* __restrict__ prho,
    const float* __restrict__ pnu, float* __restrict__ out) {
  int a = blockIdx.x;
  int bb = threadIdx.x;
  float cv0 = 0.f, cv1 = 0.f, m0 = 0.f, m1 = 0.f;
  float ka0 = 0.f, ka1 = 0.f, kc0 = 0.f, kc1 = 0.f, d0 = 0.f, d1 = 0.f;
#pragma unroll 4
  for (int i = 0; i < NOBS; i += 2) {
    float sa0 = S[i * SB + a],        sb0 = S[i * SB + bb];
    float sy0 = S[i * SB + 64],       s10 = S[i * SB + 65];
    float sa1 = S[(i + 1) * SB + a],  sb1 = S[(i + 1) * SB + bb];
    float sy1 = S[(i + 1) * SB + 64], s11 = S[(i + 1) * SB + 65];
    cv0 = fmaf(sa0, sb0, cv0);  cv1 = fmaf(sa1, sb1, cv1);
    m0 = fmaf(sa0, sy0, m0);    m1 = fmaf(sa1, sy1, m1);
    ka0 = fmaf(sa0, s10, ka0);  ka1 = fmaf(sa1, s11, ka1);
    kc0 = fmaf(sb0, s10, kc0);  kc1 = fmaf(sb1, s11, kc1);
    d0 = fmaf(s10, s10, d0);    d1 = fmaf(s11, s11, d1);
  }
  float nu = pnu[0];
  float c2 = -0.72134752044448f / prho[0];
  float qa = Cm[(NOBS + a) * NF + NOBS + a];
  float qb = Cm[(NOBS + bb) * NF + NOBS + bb];
  float cab = Cm[(NOBS + a) * NF + NOBS + bb];
  float D2 = qa + qb - 2.f * cab;
  D2 = D2 > 0.f ? D2 : 0.f;
  float kxx = nu * exp2f(c2 * D2);
  float kbxa = 1.f - (ka0 + ka1);
  float kbxb = 1.f - (kc0 + kc1);
  float den = d0 + d1;
  out[MTEST + a * MTEST + bb] = kxx - (cv0 + cv1) + kbxa * kbxb / den;
  if (bb == 0) out[a] = pb[0] + (m0 + m1);
}

extern "C" void kernel_launch(void* const* d_in, const int* in_sizes, int n_in,
                              void* d_out, int out_size, void* d_ws, size_t ws_size,
                              hipStream_t stream) {
  const float* Xo = (const float*)d_in[0];
  const float* Ao = (const float*)d_in[1];
  const float* Xt = (const float*)d_in[2];
  const float* At = (const float*)d_in[3];
  const float* ys = (const float*)d_in[4];
  const float* rb = (const float*)d_in[5];
  const float* prho = (const float*)d_in[6];
  const float* pg = (const float*)d_in[7];
  const float* pnu = (const float*)d_in[8];
  const float* pb = (const float*)d_in[9];
  float* ws = (float*)d_ws;
  float* C = ws + WS_C;
  float* S = ws + WS_S;
  float* Lbuf = ws + WS_LP;
  float* Bbuf = ws + WS_BB;
  float* out = (float*)d_out;

  hipLaunchKernelGGL(k1_C, dim3(528), dim3(256), 0, stream,
                     Xo, Ao, Xt, At, rb, C);
  hipLaunchKernelGGL(k2_build, dim3(NOBS), dim3(256), 0, stream,
                     C, ys, pb, prho, pg, pnu, Lbuf, Bbuf);
  hipLaunchKernelGGL(k3_factor_solve, dim3(1), dim3(NTHR), 0, stream,
                     Lbuf, Bbuf, S);
  hipLaunchKernelGGL(k4_post, dim3(MTEST), dim3(MTEST), 0, stream, S, C, pb, prho, pnu, out);
}

// Round 13
// 226.393 us; speedup vs baseline: 1.1537x; 1.0007x over previous
//
#include <hip/hip_runtime.h>
#include <math.h>

#define NOBS  192
#define MTEST 64
#define NF    256
#define KP    32
#define DD    8
#define NB    32                   /* Cholesky block */
#define NBLK  6
#define SB    69                   /* Bm row stride: 64 Kox + ys + ones + 3 pad */
#define PSTR  36                   /* Pn/Mi row stride (16B aligned) */
#define NTHR  512
#define NWAVE 8

/* padded packed-lower-triangle offset: rows padded to multiple of 4 floats so
   every row is 16B-aligned. PROF(191)+192 = 18816. */
__device__ __host__ __forceinline__ int PROF(int i) {
  int a = i >> 2, m = i & 3;
  return ((a + 1) * ((a << 1) + m)) << 2;
}

/* ws layout (float offsets) */
#define WS_C   0                      /* 65536 */
#define WS_S   (WS_C + NF*NF)         /* 13248 */
#define WS_LP  (WS_S + NOBS*SB)       /* 18816 packed Koo image */
#define WS_BB  (WS_LP + 18816)        /* 13248 Bm image; end 110848 floats */

// K1 (k0 fused): 8x8 function tile per block (256 thr). Computes z'=x/rho*sqrt(log2e),
// mh=-0.5||z'||^2 on the fly. i-side staged in LDS; thread owns one (j,q) point.
// C[i,j] = sum_{p,q} A[i,p]A[j,q] exp2(zp.zq + mh_p + mh_q)
__global__ __launch_bounds__(256) void k1_C(
    const float* __restrict__ Xo, const float* __restrict__ Ao,
    const float* __restrict__ Xt, const float* __restrict__ At,
    const float* __restrict__ rho_base, float* __restrict__ C) {
  // decode linear upper-triangle block index -> (ti, tj), ti<=tj (528 blocks)
  int tt = blockIdx.x;
  int ti = 0, len = 32, rm = tt;
  while (rm >= len) { rm -= len; ++ti; --len; }
  int tj = ti + rm;

  __shared__ float Zi[8 * KP * DD];   // 8KB
  __shared__ float Ai[8 * KP];
  __shared__ float MHi[8 * KP];
  int th = threadIdx.x;
  const float s = 1.2011224087864498f;  // sqrt(log2(e))
  float4 rr0 = *(const float4*)(rho_base);
  float4 rr1 = *(const float4*)(rho_base + 4);
  float i0 = s / rr0.x, i1 = s / rr0.y, i2 = s / rr0.z, i3 = s / rr0.w;
  float i4 = s / rr1.x, i5 = s / rr1.y, i6 = s / rr1.z, i7 = s / rr1.w;

  // i-side point (staged to LDS): global point index gpi = ti*256 + th
  {
    int gpi = ti * 256 + th;
    const float* xp = (gpi < NOBS * KP) ? (Xo + gpi * DD) : (Xt + (gpi - NOBS * KP) * DD);
    float4 x0 = *(const float4*)(xp);
    float4 x1 = *(const float4*)(xp + 4);
    float z0 = x0.x * i0, z1 = x0.y * i1, z2 = x0.z * i2, z3 = x0.w * i3;
    float z4 = x1.x * i4, z5 = x1.y * i5, z6 = x1.z * i6, z7 = x1.w * i7;
    float n = z0 * z0 + z1 * z1 + z2 * z2 + z3 * z3 +
              z4 * z4 + z5 * z5 + z6 * z6 + z7 * z7;
    *(float4*)&Zi[th * DD] = make_float4(z0, z1, z2, z3);
    *(float4*)&Zi[th * DD + 4] = make_float4(z4, z5, z6, z7);
    MHi[th] = -0.5f * n;
    Ai[th] = (gpi < NOBS * KP) ? Ao[gpi] : At[gpi - NOBS * KP];
  }
  // j-side point (kept in registers): gpj = tj*256 + th
  float4 zq0, zq1;
  float aq, mq;
  {
    int gpj = tj * 256 + th;
    const float* xp = (gpj < NOBS * KP) ? (Xo + gpj * DD) : (Xt + (gpj - NOBS * KP) * DD);
    float4 x0 = *(const float4*)(xp);
    float4 x1 = *(const float4*)(xp + 4);
    zq0 = make_float4(x0.x * i0, x0.y * i1, x0.z * i2, x0.w * i3);
    zq1 = make_float4(x1.x * i4, x1.y * i5, x1.z * i6, x1.w * i7);
    float n = zq0.x * zq0.x + zq0.y * zq0.y + zq0.z * zq0.z + zq0.w * zq0.w +
              zq1.x * zq1.x + zq1.y * zq1.y + zq1.z * zq1.z + zq1.w * zq1.w;
    mq = -0.5f * n;
    aq = (gpj < NOBS * KP) ? Ao[gpj] : At[gpj - NOBS * KP];
  }
  __syncthreads();

  int q = th & 31;
  float acc[8];
#pragma unroll
  for (int ii = 0; ii < 8; ++ii) acc[ii] = 0.f;
#pragma unroll
  for (int ii = 0; ii < 8; ++ii) {
    float a_ = acc[ii];
#pragma unroll 8
    for (int p = 0; p < KP; ++p) {
      const float4* Zp = (const float4*)(Zi + (ii * KP + p) * DD);
      float4 zp0 = Zp[0], zp1 = Zp[1];
      float d = zp0.x * zq0.x;
      d = fmaf(zp0.y, zq0.y, d);
      d = fmaf(zp0.z, zq0.z, d);
      d = fmaf(zp0.w, zq0.w, d);
      d = fmaf(zp1.x, zq1.x, d);
      d = fmaf(zp1.y, zq1.y, d);
      d = fmaf(zp1.z, zq1.z, d);
      d = fmaf(zp1.w, zq1.w, d);
      float arg = d + MHi[ii * KP + p] + mq;
      float ex;
      asm("v_exp_f32 %0, %1" : "=v"(ex) : "v"(arg));  // 2^arg
      a_ = fmaf(Ai[ii * KP + p], ex, a_);
    }
    acc[ii] = a_;
  }
#pragma unroll
  for (int ii = 0; ii < 8; ++ii) {
    float v = acc[ii] * aq;
#pragma unroll
    for (int off = 16; off > 0; off >>= 1) v += __shfl_xor(v, off, 64);
    if (q == 0) {
      int fi = ti * 8 + ii, fj = tj * 8 + (th >> 5);
      C[fi * NF + fj] = v;
      C[fj * NF + fi] = v;
    }
  }
}

// K2: parallel build of the LDS images for k3: Lbuf = packed-padded lower
// triangle of Koo (nugget included, pads zeroed); Bbuf = [Kox | ys-b | 1 | 0].
__global__ __launch_bounds__(256) void k2_build(
    const float* __restrict__ Cm, const float* __restrict__ ys,
    const float* __restrict__ pb, const float* __restrict__ prho,
    const float* __restrict__ pg, const float* __restrict__ pnu,
    float* __restrict__ Lbuf, float* __restrict__ Bbuf) {
  int i = blockIdx.x;   // 0..191
  int t = threadIdx.x;
  float nu = pnu[0];
  float c2 = -0.72134752044448f / prho[0];  // -0.5*log2(e)/rho
  float gn = nu * pg[0];
  float qi = Cm[i * NF + i];
  int rowlen = (i & ~3) + 4;
  int base = PROF(i);
  for (int l = t; l < rowlen; l += 256) {
    float v = 0.f;
    if (l <= i) {
      float D2 = qi + Cm[l * NF + l] - 2.f * Cm[i * NF + l];
      D2 = D2 > 0.f ? D2 : 0.f;
      v = nu * exp2f(c2 * D2) + (l == i ? gn : 0.f);
    }
    Lbuf[base + l] = v;
  }
  if (t < SB) {
    float v;
    if (t < 64) {
      float D2 = qi + Cm[(NOBS + t) * NF + NOBS + t] - 2.f * Cm[i * NF + NOBS + t];
      D2 = D2 > 0.f ? D2 : 0.f;
      v = nu * exp2f(c2 * D2);
    } else if (t == 64) v = ys[i] - pb[0];
    else if (t == 65) v = 1.0f;
    else v = 0.f;
    Bbuf[i * SB + t] = v;
  }
}

// Phase A: wave-0 lanes 0..31 factor the 32x32 diag block at kbA in registers,
// then invert; inv(L11) rows land in MiB (stride PSTR).
__device__ __forceinline__ void phaseA(float* Lp, float* MiB, int kbA, int lane) {
  float row[32];
  int base = PROF(kbA + lane) + kbA;
#pragma unroll
  for (int c = 0; c < 32; c += 4) {
    float4 v = *(const float4*)&Lp[base + c];
    row[c] = v.x; row[c + 1] = v.y; row[c + 2] = v.z; row[c + 3] = v.w;
  }
#pragma unroll
  for (int j = 0; j < 32; ++j) {
    float dj = __shfl(row[j], j, 64);
    float rs = 1.0f / sqrtf(dj);
    float cl = row[j] * rs;
    row[j] = cl;
#pragma unroll
    for (int c = j + 1; c < 32; ++c)
      row[c] = fmaf(-cl, __shfl(cl, c, 64), row[c]);
  }
#pragma unroll
  for (int c = 0; c < 32; c += 4) {
    *(float4*)&MiB[lane * PSTR + c] =
        make_float4(row[c], row[c + 1], row[c + 2], row[c + 3]);
  }
  // triangular inverse: lane holds column `lane` of M = inv(L11)
  float x[32];
#pragma unroll
  for (int i2 = 0; i2 < 32; ++i2) {
    float vi = MiB[i2 * PSTR + lane];  // lane k holds L[i2][k]
    float acc = (i2 == lane) ? 1.0f : 0.0f;
#pragma unroll
    for (int k = 0; k < 32; ++k) {
      if (k < i2) acc = fmaf(-__shfl(vi, k, 64), x[k], acc);
    }
    x[i2] = acc / __shfl(vi, i2, 64);
  }
#pragma unroll
  for (int i2 = 0; i2 < 32; ++i2) MiB[i2 * PSTR + lane] = x[i2];
}

// K3: blocked Cholesky + fused 66-RHS forward solve, 8 waves (512 thr), with
// lookahead: Phase A(b+1) on wave 0 concurrent with block b's trailing.
// __launch_bounds__(512, 2): LDS (157KB) caps us at 1 wg/CU = 2 waves/EU
// anyway, so grant the allocator the full 256-VGPR budget — R12 at the
// default 128-VGPR target still spilled ~50KB (WRITE_SIZE 103.75 vs 53).
__global__ __launch_bounds__(NTHR, 2) void k3_factor_solve(
    const float* __restrict__ Lsrc, const float* __restrict__ Bsrc,
    float* __restrict__ Sout) {
  __shared__ float Lp[18816];          // 75264 B
  __shared__ float Bm[NOBS * SB];      // 52992 B
  __shared__ float Pn[160 * PSTR];     // 23040 B
  __shared__ float Mi[2][32 * PSTR];   // 9216 B  (total 160512 B)

  int tid = threadIdx.x;
  int lane = tid & 63;
  int w = tid >> 6;

  // ---- load prebuilt images ----
  for (int e = tid; e < 18816 / 4; e += NTHR)
    ((float4*)Lp)[e] = ((const float4*)Lsrc)[e];
  for (int e = tid; e < (NOBS * SB) / 4; e += NTHR)
    ((float4*)Bm)[e] = ((const float4*)Bsrc)[e];
  __syncthreads();

  if (w == 0 && lane < 32) phaseA(Lp, Mi[0], 0, lane);
  __syncthreads();

  for (int b = 0; b < NBLK; ++b) {
    int kb = b * NB;
    int rem = NOBS - kb - NB;
    const float* Mc = Mi[b & 1];

    // ---- R1: panel L21 = A21*M^T -> Pn ; then Y = M*B_b -> registers ----
    float yv[5];
    if (rem > 0) {
      int c = tid & 31;
      int rg = tid >> 5;  // 0..15
      float Mreg[32];
#pragma unroll
      for (int qq = 0; qq < 32; qq += 4) {
        float4 v = *(const float4*)&Mc[c * PSTR + qq];
        Mreg[qq] = v.x; Mreg[qq + 1] = v.y; Mreg[qq + 2] = v.z; Mreg[qq + 3] = v.w;
      }
#pragma unroll 10
      for (int rr = 0; rr < 10; ++rr) {
        int r = rg + rr * 16;
        if (r < rem) {
          int abase = PROF(kb + NB + r) + kb;
          float a0 = 0.f, a1 = 0.f, a2 = 0.f, a3 = 0.f;
#pragma unroll
          for (int qq = 0; qq < 32; qq += 4) {
            float4 av = *(const float4*)&Lp[abase + qq];
            a0 = fmaf(av.x, Mreg[qq], a0);
            a1 = fmaf(av.y, Mreg[qq + 1], a1);
            a2 = fmaf(av.z, Mreg[qq + 2], a2);
            a3 = fmaf(av.w, Mreg[qq + 3], a3);
          }
          Pn[r * PSTR + c] = (a0 + a1) + (a2 + a3);
        }
      }
    }
    {
      int r2 = tid >> 4, cg = tid & 15;
      float Mrow[32];
#pragma unroll
      for (int qq = 0; qq < 32; qq += 4) {
        float4 v = *(const float4*)&Mc[r2 * PSTR + qq];
        Mrow[qq] = v.x; Mrow[qq + 1] = v.y; Mrow[qq + 2] = v.z; Mrow[qq + 3] = v.w;
      }
#pragma unroll 5
      for (int jj = 0; jj < 5; ++jj) {
        int col = cg + 16 * jj;
        float a0 = 0.f, a1 = 0.f, a2 = 0.f, a3 = 0.f;
        if (col < SB) {
#pragma unroll
          for (int k = 0; k < 32; k += 4) {
            a0 = fmaf(Mrow[k],     Bm[(kb + k) * SB + col], a0);
            a1 = fmaf(Mrow[k + 1], Bm[(kb + k + 1) * SB + col], a1);
            a2 = fmaf(Mrow[k + 2], Bm[(kb + k + 2) * SB + col], a2);
            a3 = fmaf(Mrow[k + 3], Bm[(kb + k + 3) * SB + col], a3);
          }
        }
        yv[jj] = (a0 + a1) + (a2 + a3);
      }
    }
    __syncthreads();

    // ---- R2: write Y ; priority trailing update of the NEXT diag block ----
    {
      int r2 = tid >> 4, cg = tid & 15;
#pragma unroll 5
      for (int jj = 0; jj < 5; ++jj) {
        int col = cg + 16 * jj;
        if (col < SB) Bm[(kb + r2) * SB + col] = yv[jj];
      }
    }
    if (rem > 0) {
      for (int idx = tid; idx < 1024; idx += NTHR) {
        int r = idx >> 5, c = idx & 31;
        if (c <= r) {
          float a0 = 0.f, a1 = 0.f, a2 = 0.f, a3 = 0.f;
#pragma unroll
          for (int qq = 0; qq < 32; qq += 4) {
            float4 u = *(const float4*)&Pn[r * PSTR + qq];
            float4 vv = *(const float4*)&Pn[c * PSTR + qq];
            a0 = fmaf(u.x, vv.x, a0);
            a1 = fmaf(u.y, vv.y, a1);
            a2 = fmaf(u.z, vv.z, a2);
            a3 = fmaf(u.w, vv.w, a3);
          }
          Lp[PROF(kb + NB + r) + kb + NB + c] -= (a0 + a1) + (a2 + a3);
        }
      }
    }
    __syncthreads();

    // ---- R3: wave0 = Phase A(b+1) (lookahead) ; others = B-trail + C-rest ----
    if (rem > 0) {
      if (w == 0) {
        if (lane < 32) phaseA(Lp, Mi[(b + 1) & 1], kb + NB, lane);
      } else {
        int wp = w - 1;  // 0..6
        // B-trail cols 0..63: lane owns one column; Y rows cached in yc[]
        float yc[32];
#pragma unroll
        for (int k = 0; k < 32; ++k) yc[k] = Bm[(kb + k) * SB + lane];
        for (int rt = wp; rt < rem; rt += (NWAVE - 1)) {
          int gr = kb + NB + rt;
          float a0 = Bm[gr * SB + lane], a1 = 0.f;
#pragma unroll
          for (int k = 0; k < 32; k += 4) {
            float4 pv = *(const float4*)&Pn[rt * PSTR + k];  // broadcast
            a0 = fmaf(-pv.x, yc[k], a0);
            a1 = fmaf(-pv.y, yc[k + 1], a1);
            a0 = fmaf(-pv.z, yc[k + 2], a0);
            a1 = fmaf(-pv.w, yc[k + 3], a1);
          }
          Bm[gr * SB + lane] = a0 + a1;
        }
        // B-trail cols 64/65: thread-per-row scalar pass (threads 64..223,
        // i.e. waves 1..3 — never wave 0)
        {
          int r65 = tid - 64;
          if (r65 >= 0 && r65 < rem) {
            int gr = kb + NB + r65;
            float a64 = Bm[gr * SB + 64], a65 = Bm[gr * SB + 65];
#pragma unroll
            for (int qq = 0; qq < 32; qq += 4) {
              float4 pv = *(const float4*)&Pn[r65 * PSTR + qq];
              a64 = fmaf(-pv.x, Bm[(kb + qq) * SB + 64], a64);
              a65 = fmaf(-pv.x, Bm[(kb + qq) * SB + 65], a65);
              a64 = fmaf(-pv.y, Bm[(kb + qq + 1) * SB + 64], a64);
              a65 = fmaf(-pv.y, Bm[(kb + qq + 1) * SB + 65], a65);
              a64 = fmaf(-pv.z, Bm[(kb + qq + 2) * SB + 64], a64);
              a65 = fmaf(-pv.z, Bm[(kb + qq + 2) * SB + 65], a65);
              a64 = fmaf(-pv.w, Bm[(kb + qq + 3) * SB + 64], a64);
              a65 = fmaf(-pv.w, Bm[(kb + qq + 3) * SB + 65], a65);
            }
            Bm[gr * SB + 64] = a64;
            Bm[gr * SB + 65] = a65;
          }
        }
        // C-rest: trailing rows 32..rem-1 (priority rows 0..31 already done)
        for (int c0 = 0; c0 < rem; c0 += 64) {
          int cc = c0 + lane;
          int ccl = cc < 160 ? cc : 159;
          float Pc[32];
#pragma unroll
          for (int qq = 0; qq < 32; qq += 4) {
            float4 v = *(const float4*)&Pn[ccl * PSTR + qq];
            Pc[qq] = v.x; Pc[qq + 1] = v.y; Pc[qq + 2] = v.z; Pc[qq + 3] = v.w;
          }
          int rstart = c0 > 32 ? c0 : 32;
          for (int r = rstart + wp; r < rem; r += (NWAVE - 1)) {
            float a0 = 0.f, a1 = 0.f, a2 = 0.f, a3 = 0.f;
#pragma unroll
            for (int qq = 0; qq < 32; qq += 4) {
              float4 u = *(const float4*)&Pn[r * PSTR + qq];  // broadcast
              a0 = fmaf(u.x, Pc[qq], a0);
              a1 = fmaf(u.y, Pc[qq + 1], a1);
              a2 = fmaf(u.z, Pc[qq + 2], a2);
              a3 = fmaf(u.w, Pc[qq + 3], a3);
            }
            float tot = (a0 + a1) + (a2 + a3);
            if (cc <= r) {
              Lp[PROF(kb + NB + r) + kb + NB + cc] -= tot;
            }
          }
        }
      }
      __syncthreads();
    }
  }

  // ---- dump S = L^-1 [Kox | ys-b | 1 | pad] ----
  for (int e = tid; e < (NOBS * SB) / 4; e += NTHR)
    ((float4*)Sout)[e] = ((const float4*)Bm)[e];
}

// K4: epilogue across 64 blocks: mean, cov from S; Kxx recomputed from C.
__global__ __launch_bounds__(64) void k4_post(
    const float* __restrict__ S, const float* __restrict__ Cm,
    const float* __restrict__ pb, const float* __restrict__ prho,
    const float* __restrict__ pnu, float* __restrict__ out) {
  int a = blockIdx.x;
  int bb = threadIdx.x;
  float cv0 = 0.f, cv1 = 0.f, m0 = 0.f, m1 = 0.f;
  float ka0 = 0.f, ka1 = 0.f, kc0 = 0.f, kc1 = 0.f, d0 = 0.f, d1 = 0.f;
#pragma unroll 4
  for (int i = 0; i < NOBS; i += 2) {
    float sa0 = S[i * SB + a],        sb0 = S[i * SB + bb];
    float sy0 = S[i * SB + 64],       s10 = S[i * SB + 65];
    float sa1 = S[(i + 1) * SB + a],  sb1 = S[(i + 1) * SB + bb];
    float sy1 = S[(i + 1) * SB + 64], s11 = S[(i + 1) * SB + 65];
    cv0 = fmaf(sa0, sb0, cv0);  cv1 = fmaf(sa1, sb1, cv1);
    m0 = fmaf(sa0, sy0, m0);    m1 = fmaf(sa1, sy1, m1);
    ka0 = fmaf(sa0, s10, ka0);  ka1 = fmaf(sa1, s11, ka1);
    kc0 = fmaf(sb0, s10, kc0);  kc1 = fmaf(sb1, s11, kc1);
    d0 = fmaf(s10, s10, d0);    d1 = fmaf(s11, s11, d1);
  }
  float nu = pnu[0];
  float c2 = -0.72134752044448f / prho[0];
  float qa = Cm[(NOBS + a) * NF + NOBS + a];
  float qb = Cm[(NOBS + bb) * NF + NOBS + bb];
  float cab = Cm[(NOBS + a) * NF + NOBS + bb];
  float D2 = qa + qb - 2.f * cab;
  D2 = D2 > 0.f ? D2 : 0.f;
  float kxx = nu * exp2f(c2 * D2);
  float kbxa = 1.f - (ka0 + ka1);
  float kbxb = 1.f - (kc0 + kc1);
  float den = d0 + d1;
  out[MTEST + a * MTEST + bb] = kxx - (cv0 + cv1) + kbxa * kbxb / den;
  if (bb == 0) out[a] = pb[0] + (m0 + m1);
}

extern "C" void kernel_launch(void* const* d_in, const int* in_sizes, int n_in,
                              void* d_out, int out_size, void* d_ws, size_t ws_size,
                              hipStream_t stream) {
  const float* Xo = (const float*)d_in[0];
  const float* Ao = (const float*)d_in[1];
  const float* Xt = (const float*)d_in[2];
  const float* At = (const float*)d_in[3];
  const float* ys = (const float*)d_in[4];
  const float* rb = (const float*)d_in[5];
  const float* prho = (const float*)d_in[6];
  const float* pg = (const float*)d_in[7];
  const float* pnu = (const float*)d_in[8];
  const float* pb = (const float*)d_in[9];
  float* ws = (float*)d_ws;
  float* C = ws + WS_C;
  float* S = ws + WS_S;
  float* Lbuf = ws + WS_LP;
  float* Bbuf = ws + WS_BB;
  float* out = (float*)d_out;

  hipLaunchKernelGGL(k1_C, dim3(528), dim3(256), 0, stream,
                     Xo, Ao, Xt, At, rb, C);
  hipLaunchKernelGGL(k2_build, dim3(NOBS), dim3(256), 0, stream,
                     C, ys, pb, prho, pg, pnu, Lbuf, Bbuf);
  hipLaunchKernelGGL(k3_factor_solve, dim3(1), dim3(NTHR), 0, stream,
                     Lbuf, Bbuf, S);
  hipLaunchKernelGGL(k4_post, dim3(MTEST), dim3(MTEST), 0, stream, S, C, pb, prho, pnu, out);
}